// Round 17
// baseline (98.859 us; speedup 1.0000x reference)
//
#include <hip/hip_runtime.h>

#define HH 128
#define NT 512
#define PT 256

typedef float  f32x4  __attribute__((ext_vector_type(4)));
typedef _Float16 f16x8 __attribute__((ext_vector_type(8)));

// pack two f32 -> u32 of 2 fp16 (RNE)
static __device__ __forceinline__ unsigned int pk16(float a, float b){
  unsigned short ha = __builtin_bit_cast(unsigned short, (_Float16)a);
  unsigned short hb = __builtin_bit_cast(unsigned short, (_Float16)b);
  return (unsigned int)ha | ((unsigned int)hb << 16);
}
static __device__ __forceinline__ float f16_to_f(unsigned short s){
  return (float)__builtin_bit_cast(_Float16, s);
}

__device__ __forceinline__ float sigf(float x){
  float t = __builtin_amdgcn_exp2f(-1.44269504089f * x);
  return __builtin_amdgcn_rcpf(1.f + t);
}
__device__ __forceinline__ float tanhf_(float x){
  float t = __builtin_amdgcn_exp2f(2.88539008178f * x);
  return 1.f - 2.f*__builtin_amdgcn_rcpf(t + 1.f);
}

// Pack W into MFMA-B-fragment order, single fp16 RNE plane each.
__global__ __launch_bounds__(PT) void prep_pack(
    const float* __restrict__ W,
    unsigned short* __restrict__ pE, unsigned short* __restrict__ pL)
{
  int idx = blockIdx.x*PT + threadIdx.x;     // 0..8191
  int l  = idx & 63;
  int kc = (idx >> 6) & 3;
  int gl = (idx >> 8) & 7;
  int wp = (idx >> 11);                      // 0..3
  int q  = gl >> 1, ft = gl & 1;
  int g  = q*128 + wp*32 + ft*16 + (l & 15);
  int kbase = kc*32 + (l >> 4)*8;

  unsigned short ev[8], lv[8];
#pragma unroll
  for (int j = 0; j < 8; ++j){
    int k = kbase + j;
    float w0 = W[g*256 + k];
    float w1 = W[g*256 + 128 + k];
    float we = w0 + 0.5f*w1;
    ev[j] = __builtin_bit_cast(unsigned short, (_Float16)we);
    lv[j] = __builtin_bit_cast(unsigned short, (_Float16)w1);
  }
  long base = (long)idx*8;
  *(f16x8*)&pE[base] = *(f16x8*)ev;
  *(f16x8*)&pL[base] = *(f16x8*)lv;
}

// -------- leaf2: L0 (leaf cell) + L1 fused; both B packs resident ----------
__global__ __launch_bounds__(NT, 2) void leaf2(
    const float* __restrict__ x_leaf,
    const unsigned short* __restrict__ pL, const unsigned short* __restrict__ pE,
    const float* __restrict__ bias,
    unsigned short* __restrict__ HpO,
    float* __restrict__ csO, int ntiles)
{
  __shared__ unsigned short AsH[2][32*HH];   // leaf x, fp16, dbuf (16KB)
  __shared__ unsigned short HsF[16*HH];      // L0 pair-sum h, fp16 (4KB)
  __shared__ float          CsF[16*HH];      // L0 pair-sum c, f32 (8KB)

  const int t = threadIdx.x, w = t>>6, l = t&63;
  const int a = l>>4, fcol = l&15, feat = w*16 + fcol;

  // resident leaf-B (gates i,g,o): 12 frags; resident eff-B: 16 frags
  f16x8 rb0[3][4], rb1[4][4];
#pragma unroll
  for (int qq = 0; qq < 3; ++qq)
#pragma unroll
    for (int kc = 0; kc < 4; ++kc){
      long off = ((long)((((w>>1)*8) + (qq+1)*2 + (w&1))*4 + kc)*64 + l)*8;
      rb0[qq][kc] = *(const f16x8*)&pL[off];
    }
#pragma unroll
  for (int q = 0; q < 4; ++q)
#pragma unroll
    for (int kc = 0; kc < 4; ++kc){
      long off = ((long)((((w>>1)*8) + q*2 + (w&1))*4 + kc)*64 + l)*8;
      rb1[q][kc] = *(const f16x8*)&pE[off];
    }
  float B4[4];
#pragma unroll
  for (int q = 0; q < 4; ++q) B4[q] = bias[q*HH + feat];

  const int srow = t>>4, sci = t&15;
  float sv[8];
  auto sload = [&](int tile){
    long base = ((long)tile*32 + srow)*HH + sci*8;
    *(float4*)&sv[0] = *(const float4*)&x_leaf[base];
    *(float4*)&sv[4] = *(const float4*)&x_leaf[base+4];
  };
  auto swrite = [&](int buf){
    unsigned int hp[4];
#pragma unroll
    for (int p = 0; p < 4; ++p) hp[p] = pk16(sv[2*p], sv[2*p+1]);
    uint4 hq = {hp[0],hp[1],hp[2],hp[3]};
    int off = srow*256 + ((sci*16) ^ ((srow&7)<<4));
    *(uint4*)((char*)&AsH[buf][0] + off) = hq;
  };

  int tile = blockIdx.x;
  if (tile < ntiles){ sload(tile); swrite(0); }
  __syncthreads();
  int buf = 0;

  for (; tile < ntiles; tile += gridDim.x){
#pragma unroll
    for (int qq = 0; qq < 3; ++qq)
#pragma unroll
      for (int kc = 0; kc < 4; ++kc)
        asm volatile("" : "+v"(rb0[qq][kc]));
#pragma unroll
    for (int q = 0; q < 4; ++q)
#pragma unroll
      for (int kc = 0; kc < 4; ++kc)
        asm volatile("" : "+v"(rb1[q][kc]));

    int nxt = tile + gridDim.x;
    bool have = nxt < ntiles;
    if (have) sload(nxt);

    // ---- MFMA-0: L0 over 32 leaf rows (3 gates) ----
    f32x4 acc0[2][3];
#pragma unroll
    for (int mt = 0; mt < 2; ++mt)
#pragma unroll
      for (int qq = 0; qq < 3; ++qq) acc0[mt][qq] = (f32x4)(0.f);

#pragma unroll
    for (int kc = 0; kc < 4; ++kc){
      f16x8 aH[2];
#pragma unroll
      for (int mt = 0; mt < 2; ++mt){
        int row = mt*16 + fcol;
        int off = row*256 + ((kc*64 + a*16) ^ ((row&7)<<4));
        aH[mt] = *(const f16x8*)((const char*)&AsH[buf][0] + off);
      }
#pragma unroll
      for (int qq = 0; qq < 3; ++qq)
#pragma unroll
        for (int mt = 0; mt < 2; ++mt)
          acc0[mt][qq] = __builtin_amdgcn_mfma_f32_16x16x32_f16(aH[mt], rb0[qq][kc], acc0[mt][qq], 0, 0, 0);
    }

    // ---- epilogue-0: leaf cell (cc=0), pair-sums -> LDS (f16 h, f32 c) ----
#pragma unroll
    for (int mt = 0; mt < 2; ++mt){
      float hv[4], cv[4];
#pragma unroll
      for (int rr = 0; rr < 4; ++rr){
        float iv = acc0[mt][0][rr] + B4[1];
        float gv = acc0[mt][1][rr] + B4[2];
        float ov = acc0[mt][2][rr] + B4[3];
        float c = sigf(iv)*tanhf_(gv);
        float h = sigf(ov)*tanhf_(c);
        hv[rr] = h; cv[rr] = c;
      }
#pragma unroll
      for (int p = 0; p < 2; ++p){
        int row1 = mt*8 + a*2 + p;
        float hs = hv[2*p] + hv[2*p+1];
        *(unsigned short*)((char*)HsF + row1*256 + ((feat*2) ^ ((row1&7)<<4))) =
            __builtin_bit_cast(unsigned short, (_Float16)hs);
        *(float*)((char*)CsF + row1*512 + ((feat*4) ^ ((row1&7)<<4))) =
            cv[2*p] + cv[2*p+1];
      }
    }
    if (have) swrite(buf^1);
    __syncthreads();

    // ---- MFMA-1: L1 over 16 rows (4 gates), A direct from f16 LDS ----
    f32x4 acc1[4];
#pragma unroll
    for (int q = 0; q < 4; ++q) acc1[q] = (f32x4)(0.f);
#pragma unroll
    for (int kc = 0; kc < 4; ++kc){
      int off = fcol*256 + ((kc*64 + a*16) ^ ((fcol&7)<<4));
      f16x8 a1H = *(const f16x8*)((const char*)HsF + off);
#pragma unroll
      for (int q = 0; q < 4; ++q)
        acc1[q] = __builtin_amdgcn_mfma_f32_16x16x32_f16(a1H, rb1[q][kc], acc1[q], 0, 0, 0);
    }

    // ---- epilogue-1 -> global planes ----
    {
      float hv[4], cv[4];
#pragma unroll
      for (int rr = 0; rr < 4; ++rr){
        int n = a*4 + rr;
        float ccv = *(const float*)((const char*)CsF + n*512 + ((feat*4) ^ ((n&7)<<4)));
        float fv = acc1[0][rr] + B4[0];
        float iv = acc1[1][rr] + B4[1];
        float gv = acc1[2][rr] + B4[2];
        float ov = acc1[3][rr] + B4[3];
        float c = sigf(fv)*ccv + sigf(iv)*tanhf_(gv);
        float h = sigf(ov)*tanhf_(c);
        hv[rr] = h; cv[rr] = c;
      }
#pragma unroll
      for (int p = 0; p < 2; ++p){
        long prow = (long)tile*8 + a*2 + p;
        float hs = hv[2*p] + hv[2*p+1];
        HpO[prow*HH + feat] = __builtin_bit_cast(unsigned short, (_Float16)hs);
        csO[prow*HH + feat] = cv[2*p] + cv[2*p+1];
      }
    }
    __syncthreads();
    buf ^= 1;
  }
}

// -------- fused 2-level internal kernel, f16 inter-level LDS ---------------
__global__ __launch_bounds__(NT, 2) void fuse2(
    const unsigned short* __restrict__ hPH,
    const float* __restrict__ cP,
    const unsigned short* __restrict__ pE,
    const float* __restrict__ bias,
    unsigned short* __restrict__ HpO,
    float* __restrict__ csO, int ntiles)
{
  __shared__ unsigned short AsH[2][32*HH];
  __shared__ unsigned short HsF[16*HH];
  __shared__ float          CsF[16*HH];

  const int t = threadIdx.x, w = t>>6, l = t&63;
  const int a = l>>4, fcol = l&15, feat = w*16 + fcol;

  f16x8 rb[4][4];
#pragma unroll
  for (int q = 0; q < 4; ++q)
#pragma unroll
    for (int kc = 0; kc < 4; ++kc){
      long off = ((long)((((w>>1)*8) + q*2 + (w&1))*4 + kc)*64 + l)*8;
      rb[q][kc] = *(const f16x8*)&pE[off];
    }
  float B4[4];
#pragma unroll
  for (int q = 0; q < 4; ++q) B4[q] = bias[q*HH + feat];

  const int srow = t>>4, sci = t&15;
  f16x8 svH;
  auto sload = [&](int tile){
    long base = ((long)tile*32 + srow)*HH + sci*8;
    svH = *(const f16x8*)&hPH[base];
  };
  auto swrite = [&](int buf){
    int off = srow*256 + ((sci*16) ^ ((srow&7)<<4));
    *(f16x8*)((char*)&AsH[buf][0] + off) = svH;
  };

  int tile = blockIdx.x;
  if (tile < ntiles){ sload(tile); swrite(0); }
  __syncthreads();
  int buf = 0;

  for (; tile < ntiles; tile += gridDim.x){
#pragma unroll
    for (int q = 0; q < 4; ++q)
#pragma unroll
      for (int kc = 0; kc < 4; ++kc)
        asm volatile("" : "+v"(rb[q][kc]));

    int nxt = tile + gridDim.x;
    bool have = nxt < ntiles;

    float cc0[2][4];
#pragma unroll
    for (int mt = 0; mt < 2; ++mt)
#pragma unroll
      for (int rr = 0; rr < 4; ++rr)
        cc0[mt][rr] = cP[((long)tile*32 + mt*16 + a*4 + rr)*HH + feat];

    if (have) sload(nxt);

    // ---- MFMA-0: level A over 32 rows ----
    f32x4 acc0[2][4];
#pragma unroll
    for (int mt = 0; mt < 2; ++mt)
#pragma unroll
      for (int q = 0; q < 4; ++q) acc0[mt][q] = (f32x4)(0.f);

#pragma unroll
    for (int kc = 0; kc < 4; ++kc){
      f16x8 aH[2];
#pragma unroll
      for (int mt = 0; mt < 2; ++mt){
        int row = mt*16 + fcol;
        int off = row*256 + ((kc*64 + a*16) ^ ((row&7)<<4));
        aH[mt] = *(const f16x8*)((const char*)&AsH[buf][0] + off);
      }
#pragma unroll
      for (int q = 0; q < 4; ++q)
#pragma unroll
        for (int mt = 0; mt < 2; ++mt)
          acc0[mt][q] = __builtin_amdgcn_mfma_f32_16x16x32_f16(aH[mt], rb[q][kc], acc0[mt][q], 0, 0, 0);
    }

    // ---- epilogue-0 -> LDS pair-sums (f16 h, f32 c) ----
#pragma unroll
    for (int mt = 0; mt < 2; ++mt){
      float hv[4], cv[4];
#pragma unroll
      for (int rr = 0; rr < 4; ++rr){
        float fv = acc0[mt][0][rr] + B4[0];
        float iv = acc0[mt][1][rr] + B4[1];
        float gv = acc0[mt][2][rr] + B4[2];
        float ov = acc0[mt][3][rr] + B4[3];
        float c = sigf(fv)*cc0[mt][rr] + sigf(iv)*tanhf_(gv);
        float h = sigf(ov)*tanhf_(c);
        hv[rr] = h; cv[rr] = c;
      }
#pragma unroll
      for (int p = 0; p < 2; ++p){
        int row1 = mt*8 + a*2 + p;
        float hs = hv[2*p] + hv[2*p+1];
        *(unsigned short*)((char*)HsF + row1*256 + ((feat*2) ^ ((row1&7)<<4))) =
            __builtin_bit_cast(unsigned short, (_Float16)hs);
        *(float*)((char*)CsF + row1*512 + ((feat*4) ^ ((row1&7)<<4))) =
            cv[2*p] + cv[2*p+1];
      }
    }
    if (have) swrite(buf^1);
    __syncthreads();

    // ---- MFMA-1: level B over 16 rows, A direct from f16 LDS ----
    f32x4 acc1[4];
#pragma unroll
    for (int q = 0; q < 4; ++q) acc1[q] = (f32x4)(0.f);
#pragma unroll
    for (int kc = 0; kc < 4; ++kc){
      int off = fcol*256 + ((kc*64 + a*16) ^ ((fcol&7)<<4));
      f16x8 a1H = *(const f16x8*)((const char*)HsF + off);
#pragma unroll
      for (int q = 0; q < 4; ++q)
        acc1[q] = __builtin_amdgcn_mfma_f32_16x16x32_f16(a1H, rb[q][kc], acc1[q], 0, 0, 0);
    }

    // ---- epilogue-1 -> global planes ----
    {
      float hv[4], cv[4];
#pragma unroll
      for (int rr = 0; rr < 4; ++rr){
        int n = a*4 + rr;
        float ccv = *(const float*)((const char*)CsF + n*512 + ((feat*4) ^ ((n&7)<<4)));
        float fv = acc1[0][rr] + B4[0];
        float iv = acc1[1][rr] + B4[1];
        float gv = acc1[2][rr] + B4[2];
        float ov = acc1[3][rr] + B4[3];
        float c = sigf(fv)*ccv + sigf(iv)*tanhf_(gv);
        float h = sigf(ov)*tanhf_(c);
        hv[rr] = h; cv[rr] = c;
      }
#pragma unroll
      for (int p = 0; p < 2; ++p){
        long prow = (long)tile*8 + a*2 + p;
        float hs = hv[2*p] + hv[2*p+1];
        HpO[prow*HH + feat] = __builtin_bit_cast(unsigned short, (_Float16)hs);
        csO[prow*HH + feat] = cv[2*p] + cv[2*p+1];
      }
    }
    __syncthreads();
    buf ^= 1;
  }
}

// -------- multi-level tail block (single-plane A; zero-pad for ROWS0<16) ---
template<int ROWS0, int NLEV, int INPLANES, int FINAL>
__global__ __launch_bounds__(NT, 2) void treeblk2(
    const unsigned short* __restrict__ Hp,
    const float* __restrict__ cs,
    const float* __restrict__ hraw, const float* __restrict__ craw,
    const unsigned short* __restrict__ pE,
    const float* __restrict__ bias,
    float* __restrict__ h_out, float* __restrict__ c_out,
    float* __restrict__ root_out)
{
  constexpr int MT = (ROWS0 >= 16) ? (ROWS0/16) : 1;
  constexpr int AR = (ROWS0 < 16) ? 16 : ROWS0;
  __shared__ float Asum[AR][132];
  __shared__ float Csum[AR][132];

  const int t = threadIdx.x;
  const long blk = blockIdx.x;
  const int w = t >> 6, l = t & 63;
  const int a = l >> 4, fcol = l & 15, feat = w*16 + fcol;

  {
    constexpr int EPT = ROWS0*HH/NT;
    constexpr int TPR = HH/EPT;
    int row = t/TPR, c0 = (t%TPR)*EPT;
    if (INPLANES){
      long base = (blk*ROWS0 + row)*(long)HH + c0;
#pragma unroll
      for (int j = 0; j < EPT; ++j){
        Asum[row][c0+j] = f16_to_f(Hp[base+j]);
        Csum[row][c0+j] = cs[base+j];
      }
    } else {
      long g = (blk*2*ROWS0 + 2*row)*(long)HH + c0;
#pragma unroll
      for (int j = 0; j < EPT; ++j){
        Asum[row][c0+j] = hraw[g+j] + hraw[g+HH+j];
        Csum[row][c0+j] = craw[g+j] + craw[g+HH+j];
      }
    }
    if (ROWS0 < 16){
      int prow2 = ROWS0 + row;
      if (prow2 < 16){
#pragma unroll
        for (int j = 0; j < EPT; ++j){
          Asum[prow2][c0+j] = 0.f;
          Csum[prow2][c0+j] = 0.f;
        }
      }
    }
  }

  f16x8 rb[4][4];
#pragma unroll
  for (int q = 0; q < 4; ++q)
#pragma unroll
    for (int kc = 0; kc < 4; ++kc){
      long off = ((long)((((w>>1)*8) + q*2 + (w&1))*4 + kc)*64 + l)*8;
      rb[q][kc] = *(const f16x8*)&pE[off];
    }
  float B4[4];
#pragma unroll
  for (int q = 0; q < 4; ++q) B4[q] = bias[q*HH + feat];

  __syncthreads();

#pragma unroll
  for (int lv = 0; lv < NLEV; ++lv){
    const int rows  = ROWS0 >> lv;
    const int tiles = (rows >= 16) ? (rows/16) : 1;
    float hv[MT][4], cv[MT][4];

#pragma unroll
    for (int mt = 0; mt < MT; ++mt){
      if (mt >= tiles) continue;
      f16x8 aH[4];
#pragma unroll
      for (int kc = 0; kc < 4; ++kc){
        const float* ap = &Asum[mt*16 + fcol][kc*32 + a*8];
        float av[8];
        *(float4*)&av[0] = *(const float4*)&ap[0];
        *(float4*)&av[4] = *(const float4*)&ap[4];
        unsigned int hp[4];
#pragma unroll
        for (int p = 0; p < 4; ++p) hp[p] = pk16(av[2*p], av[2*p+1]);
        uint4 hq = {hp[0],hp[1],hp[2],hp[3]};
        aH[kc] = *(f16x8*)&hq;
      }
      f32x4 acc[4];
#pragma unroll
      for (int q = 0; q < 4; ++q) acc[q] = (f32x4)(0.f);
#pragma unroll
      for (int kc = 0; kc < 4; ++kc){
#pragma unroll
        for (int q = 0; q < 4; ++q)
          acc[q] = __builtin_amdgcn_mfma_f32_16x16x32_f16(aH[kc], rb[q][kc], acc[q], 0, 0, 0);
      }
#pragma unroll
      for (int rr = 0; rr < 4; ++rr){
        int n = mt*16 + a*4 + rr;
        float ccv = Csum[n][feat];
        float fv = acc[0][rr] + B4[0];
        float iv = acc[1][rr] + B4[1];
        float gv = acc[2][rr] + B4[2];
        float ov = acc[3][rr] + B4[3];
        float c = sigf(fv)*ccv + sigf(iv)*tanhf_(gv);
        float h = sigf(ov)*tanhf_(c);
        hv[mt][rr] = h; cv[mt][rr] = c;
      }
    }
    __syncthreads();

    if (lv < NLEV-1){
#pragma unroll
      for (int mt = 0; mt < MT; ++mt){
        if (mt >= tiles) continue;
#pragma unroll
        for (int p = 0; p < 2; ++p){
          int n0 = mt*16 + a*4 + 2*p;
          if (n0 < rows){
            int prow = n0 >> 1;
            Asum[prow][feat] = hv[mt][2*p] + hv[mt][2*p+1];
            Csum[prow][feat] = cv[mt][2*p] + cv[mt][2*p+1];
          }
        }
      }
      __syncthreads();
    } else if (FINAL){
      if (a == 0) root_out[feat] = hv[0][0];
    } else {
      if (a == 0){
        h_out[blk*HH + feat] = hv[0][0];
        c_out[blk*HH + feat] = cv[0][0];
      }
    }
  }
}

extern "C" void kernel_launch(void* const* d_in, const int* in_sizes, int n_in,
                              void* d_out, int out_size, void* d_ws, size_t ws_size,
                              hipStream_t stream){
  const float* leaf = (const float*)d_in[0];   // 131072 x 128 f32
  const float* W    = (const float*)d_in[1];   // 512 x 256 f32
  const float* bias = (const float*)d_in[2];   // 512 f32
  float* out = (float*)d_out;                  // 128 f32

  unsigned short* pE  = (unsigned short*)d_ws;      // 65536 u16 each
  unsigned short* pL  = pE + 65536;
  unsigned short* HpA = pL + 65536;                 // 2^15 x 128 u16
  unsigned short* HpB = HpA + (1l<<15)*HH;          // 2^13 x 128 u16
  float* csA = (float*)(HpB + (1l<<13)*HH);         // 2^15 x 128 f32
  float* csB = csA + (1l<<15)*HH;                   // 2^13 x 128 f32
  float* h16 = csB + (1l<<13)*HH;                   // 16 x 128 f32
  float* c16 = h16 + 16*HH;

  prep_pack<<<32, PT, 0, stream>>>(W, pE, pL);

  // L0+L1: 2^17 leaves -> 2^15 pair-rows
  leaf2<<<512, NT, 0, stream>>>(leaf, pL, pE, bias, HpA, csA, 4096);
  // L2+L3: 2^15 rows -> 2^13
  fuse2<<<512, NT, 0, stream>>>(HpA, csA, pE, bias, HpB, csB, 1024);
  // L4+L5: 2^13 -> 2^11
  fuse2<<<256, NT, 0, stream>>>(HpB, csB, pE, bias, HpA, csA, 256);
  // L6+L7: 2^11 -> 2^9
  fuse2<<<64, NT, 0, stream>>>(HpA, csA, pE, bias, HpB, csB, 64);
  // L8..L13: 2^9 pair-rows -> 16 raw nodes
  treeblk2<32,6,1,0><<<16, NT, 0, stream>>>(HpB, csB, nullptr, nullptr,
                                            pE, bias, h16, c16, nullptr);
  // L14..L17: 16 raw children -> root
  treeblk2<8,4,0,1><<<1, NT, 0, stream>>>(nullptr, nullptr, h16, c16,
                                          pE, bias, nullptr, nullptr, out);

  (void)in_sizes; (void)n_in; (void)out_size; (void)ws_size;
}

// Round 18
// 93.795 us; speedup vs baseline: 1.0540x; 1.0540x over previous
//
#include <hip/hip_runtime.h>

#define HH 128
#define NT 512
#define PT 256

typedef float  f32x4  __attribute__((ext_vector_type(4)));
typedef _Float16 f16x8 __attribute__((ext_vector_type(8)));

// pack two f32 -> u32 of 2 fp16 (RNE)
static __device__ __forceinline__ unsigned int pk16(float a, float b){
  unsigned short ha = __builtin_bit_cast(unsigned short, (_Float16)a);
  unsigned short hb = __builtin_bit_cast(unsigned short, (_Float16)b);
  return (unsigned int)ha | ((unsigned int)hb << 16);
}
static __device__ __forceinline__ float f16_to_f(unsigned short s){
  return (float)__builtin_bit_cast(_Float16, s);
}

#define K1 1.44269504089f
#define K2 2.88539008178f

// sig(s)*tanh(t) with ONE rcp: (1-e2)/((1+e1)(1+e2))
static __device__ __forceinline__ float sig_tanh(float s, float t){
  float e1 = __builtin_amdgcn_exp2f(-K1*s);
  float e2 = __builtin_amdgcn_exp2f(-K2*t);
  return (1.f - e2) * __builtin_amdgcn_rcpf((1.f + e1)*(1.f + e2));
}
// internal cell c-update with ONE rcp:
// c = sig(f)*cc + sig(i)*tanh(g)
//   = (cc*(1+ei)(1+eg) + (1-eg)(1+ef)) / ((1+ef)(1+ei)(1+eg))
static __device__ __forceinline__ float cell_c(float fv, float iv, float gv, float cc){
  float ef = __builtin_amdgcn_exp2f(-K1*fv);
  float ei = __builtin_amdgcn_exp2f(-K1*iv);
  float eg = __builtin_amdgcn_exp2f(-K2*gv);
  float pig = (1.f + ei)*(1.f + eg);
  return (cc*pig + (1.f - eg)*(1.f + ef)) * __builtin_amdgcn_rcpf((1.f + ef)*pig);
}

// Pack W into MFMA-B-fragment order, single fp16 RNE plane each.
__global__ __launch_bounds__(PT) void prep_pack(
    const float* __restrict__ W,
    unsigned short* __restrict__ pE, unsigned short* __restrict__ pL)
{
  int idx = blockIdx.x*PT + threadIdx.x;     // 0..8191
  int l  = idx & 63;
  int kc = (idx >> 6) & 3;
  int gl = (idx >> 8) & 7;
  int wp = (idx >> 11);                      // 0..3
  int q  = gl >> 1, ft = gl & 1;
  int g  = q*128 + wp*32 + ft*16 + (l & 15);
  int kbase = kc*32 + (l >> 4)*8;

  unsigned short ev[8], lv[8];
#pragma unroll
  for (int j = 0; j < 8; ++j){
    int k = kbase + j;
    float w0 = W[g*256 + k];
    float w1 = W[g*256 + 128 + k];
    float we = w0 + 0.5f*w1;
    ev[j] = __builtin_bit_cast(unsigned short, (_Float16)we);
    lv[j] = __builtin_bit_cast(unsigned short, (_Float16)w1);
  }
  long base = (long)idx*8;
  *(f16x8*)&pE[base] = *(f16x8*)ev;
  *(f16x8*)&pL[base] = *(f16x8*)lv;
}

// ---------------- leaf kernel: L0 only, single-plane fp16 A ------------------
__global__ __launch_bounds__(NT, 2) void leafK(
    const float* __restrict__ x_leaf,
    const unsigned short* __restrict__ pL,
    const float* __restrict__ bias,
    unsigned short* __restrict__ HpO,
    float* __restrict__ csO, int ntiles)
{
  __shared__ unsigned short AsH[2][32*HH];

  const int t = threadIdx.x, w = t>>6, l = t&63;
  const int a = l>>4, fcol = l&15, feat = w*16 + fcol;

  // resident leaf-B (gates i,g,o): 12 frags = 48 VGPRs
  f16x8 rb[3][4];
#pragma unroll
  for (int qq = 0; qq < 3; ++qq)
#pragma unroll
    for (int kc = 0; kc < 4; ++kc){
      long off = ((long)((((w>>1)*8) + (qq+1)*2 + (w&1))*4 + kc)*64 + l)*8;
      rb[qq][kc] = *(const f16x8*)&pL[off];
    }
  const float Bi = bias[HH + feat], Bg = bias[2*HH + feat], Bo = bias[3*HH + feat];

  const int srow = t>>4, sci = t&15;
  float sv[8];
  auto sload = [&](int tile){
    long base = ((long)tile*32 + srow)*HH + sci*8;
    *(float4*)&sv[0] = *(const float4*)&x_leaf[base];
    *(float4*)&sv[4] = *(const float4*)&x_leaf[base+4];
  };
  auto swrite = [&](int buf){
    unsigned int hp[4];
#pragma unroll
    for (int p = 0; p < 4; ++p) hp[p] = pk16(sv[2*p], sv[2*p+1]);
    uint4 hq = {hp[0],hp[1],hp[2],hp[3]};
    int off = srow*256 + ((sci*16) ^ ((srow&7)<<4));
    *(uint4*)((char*)&AsH[buf][0] + off) = hq;
  };

  int tile = blockIdx.x;
  if (tile < ntiles){ sload(tile); swrite(0); }
  __syncthreads();
  int buf = 0;

  for (; tile < ntiles; tile += gridDim.x){
    // keep B loop-carried
#pragma unroll
    for (int qq = 0; qq < 3; ++qq)
#pragma unroll
      for (int kc = 0; kc < 4; ++kc)
        asm volatile("" : "+v"(rb[qq][kc]));

    int nxt = tile + gridDim.x;
    bool have = nxt < ntiles;
    if (have) sload(nxt);

    f32x4 acc[2][3];
#pragma unroll
    for (int mt = 0; mt < 2; ++mt)
#pragma unroll
      for (int qq = 0; qq < 3; ++qq) acc[mt][qq] = (f32x4)(0.f);

#pragma unroll
    for (int kc = 0; kc < 4; ++kc){
      f16x8 aH[2];
#pragma unroll
      for (int mt = 0; mt < 2; ++mt){
        int row = mt*16 + fcol;
        int off = row*256 + ((kc*64 + a*16) ^ ((row&7)<<4));
        aH[mt] = *(const f16x8*)((const char*)&AsH[buf][0] + off);
      }
#pragma unroll
      for (int qq = 0; qq < 3; ++qq)
#pragma unroll
        for (int mt = 0; mt < 2; ++mt)
          acc[mt][qq] = __builtin_amdgcn_mfma_f32_16x16x32_f16(aH[mt], rb[qq][kc], acc[mt][qq], 0, 0, 0);
    }

    // epilogue (cc = 0): c = sig(i)tanh(g); h = sig(o)tanh(c)
#pragma unroll
    for (int mt = 0; mt < 2; ++mt){
      float hv[4], cv[4];
#pragma unroll
      for (int rr = 0; rr < 4; ++rr){
        float iv = acc[mt][0][rr] + Bi;
        float gv = acc[mt][1][rr] + Bg;
        float ov = acc[mt][2][rr] + Bo;
        float c = sig_tanh(iv, gv);
        float h = sig_tanh(ov, c);
        hv[rr] = h; cv[rr] = c;
      }
#pragma unroll
      for (int p = 0; p < 2; ++p){
        long prow = (long)tile*16 + mt*8 + a*2 + p;
        float hs = hv[2*p] + hv[2*p+1];
        HpO[prow*HH + feat] = __builtin_bit_cast(unsigned short, (_Float16)hs);
        csO[prow*HH + feat] = cv[2*p] + cv[2*p+1];
      }
    }

    if (have) swrite(buf^1);
    __syncthreads();
    buf ^= 1;
  }
}

// ---------------- fused 2-level internal kernel, single-plane fp16 A --------
__global__ __launch_bounds__(NT, 2) void fuse2(
    const unsigned short* __restrict__ hPH,
    const float* __restrict__ cP,
    const unsigned short* __restrict__ pE,
    const float* __restrict__ bias,
    unsigned short* __restrict__ HpO,
    float* __restrict__ csO, int ntiles)
{
  __shared__ unsigned short AsH[2][32*HH];
  __shared__ float HsF[16*HH];
  __shared__ float CsF[16*HH];

  const int t = threadIdx.x, w = t>>6, l = t&63;
  const int a = l>>4, fcol = l&15, feat = w*16 + fcol;

  f16x8 rb[4][4];   // 16 frags = 64 VGPR
#pragma unroll
  for (int q = 0; q < 4; ++q)
#pragma unroll
    for (int kc = 0; kc < 4; ++kc){
      long off = ((long)((((w>>1)*8) + q*2 + (w&1))*4 + kc)*64 + l)*8;
      rb[q][kc] = *(const f16x8*)&pE[off];
    }
  float B4[4];
#pragma unroll
  for (int q = 0; q < 4; ++q) B4[q] = bias[q*HH + feat];

  const int srow = t>>4, sci = t&15;
  f16x8 svH;
  auto sload = [&](int tile){
    long base = ((long)tile*32 + srow)*HH + sci*8;
    svH = *(const f16x8*)&hPH[base];
  };
  auto swrite = [&](int buf){
    int off = srow*256 + ((sci*16) ^ ((srow&7)<<4));
    *(f16x8*)((char*)&AsH[buf][0] + off) = svH;
  };

  int tile = blockIdx.x;
  if (tile < ntiles){ sload(tile); swrite(0); }
  __syncthreads();
  int buf = 0;

  for (; tile < ntiles; tile += gridDim.x){
#pragma unroll
    for (int q = 0; q < 4; ++q)
#pragma unroll
      for (int kc = 0; kc < 4; ++kc)
        asm volatile("" : "+v"(rb[q][kc]));

    int nxt = tile + gridDim.x;
    bool have = nxt < ntiles;

    float cc0[2][4];
#pragma unroll
    for (int mt = 0; mt < 2; ++mt)
#pragma unroll
      for (int rr = 0; rr < 4; ++rr)
        cc0[mt][rr] = cP[((long)tile*32 + mt*16 + a*4 + rr)*HH + feat];

    if (have) sload(nxt);

    // ---- MFMA-0: level A over 32 rows ----
    f32x4 acc0[2][4];
#pragma unroll
    for (int mt = 0; mt < 2; ++mt)
#pragma unroll
      for (int q = 0; q < 4; ++q) acc0[mt][q] = (f32x4)(0.f);

#pragma unroll
    for (int kc = 0; kc < 4; ++kc){
      f16x8 aH[2];
#pragma unroll
      for (int mt = 0; mt < 2; ++mt){
        int row = mt*16 + fcol;
        int off = row*256 + ((kc*64 + a*16) ^ ((row&7)<<4));
        aH[mt] = *(const f16x8*)((const char*)&AsH[buf][0] + off);
      }
#pragma unroll
      for (int q = 0; q < 4; ++q)
#pragma unroll
        for (int mt = 0; mt < 2; ++mt)
          acc0[mt][q] = __builtin_amdgcn_mfma_f32_16x16x32_f16(aH[mt], rb[q][kc], acc0[mt][q], 0, 0, 0);
    }

    // ---- epilogue-0 -> LDS pair-sums (swizzled fp32) ----
#pragma unroll
    for (int mt = 0; mt < 2; ++mt){
      float hv[4], cv[4];
#pragma unroll
      for (int rr = 0; rr < 4; ++rr){
        float fv = acc0[mt][0][rr] + B4[0];
        float iv = acc0[mt][1][rr] + B4[1];
        float gv = acc0[mt][2][rr] + B4[2];
        float ov = acc0[mt][3][rr] + B4[3];
        float c = cell_c(fv, iv, gv, cc0[mt][rr]);
        float h = sig_tanh(ov, c);
        hv[rr] = h; cv[rr] = c;
      }
#pragma unroll
      for (int p = 0; p < 2; ++p){
        int row1 = mt*8 + a*2 + p;
        int o1 = row1*512 + ((feat*4) ^ ((row1&7)<<4));
        *(float*)((char*)HsF + o1) = hv[2*p] + hv[2*p+1];
        *(float*)((char*)CsF + o1) = cv[2*p] + cv[2*p+1];
      }
    }
    if (have) swrite(buf^1);
    __syncthreads();

    // ---- MFMA-1: level B over 16 rows ----
    f32x4 acc1[4];
#pragma unroll
    for (int q = 0; q < 4; ++q) acc1[q] = (f32x4)(0.f);

#pragma unroll
    for (int kc = 0; kc < 4; ++kc){
      f16x8 a1H;
      {
        int cb = kc*128 + a*32;
        const char* base = (const char*)HsF + fcol*512;
        float av[8];
        *(float4*)&av[0] = *(const float4*)(base + ( cb       ^ ((fcol&7)<<4)));
        *(float4*)&av[4] = *(const float4*)(base + ((cb + 16) ^ ((fcol&7)<<4)));
        unsigned int hp[4];
#pragma unroll
        for (int p = 0; p < 4; ++p) hp[p] = pk16(av[2*p], av[2*p+1]);
        uint4 hq = {hp[0],hp[1],hp[2],hp[3]};
        a1H = *(f16x8*)&hq;
      }
#pragma unroll
      for (int q = 0; q < 4; ++q)
        acc1[q] = __builtin_amdgcn_mfma_f32_16x16x32_f16(a1H, rb[q][kc], acc1[q], 0, 0, 0);
    }

    // ---- epilogue-1 -> global planes ----
    {
      float hv[4], cv[4];
#pragma unroll
      for (int rr = 0; rr < 4; ++rr){
        int n = a*4 + rr;
        float ccv = *(const float*)((const char*)CsF + n*512 + ((feat*4) ^ ((n&7)<<4)));
        float fv = acc1[0][rr] + B4[0];
        float iv = acc1[1][rr] + B4[1];
        float gv = acc1[2][rr] + B4[2];
        float ov = acc1[3][rr] + B4[3];
        float c = cell_c(fv, iv, gv, ccv);
        float h = sig_tanh(ov, c);
        hv[rr] = h; cv[rr] = c;
      }
#pragma unroll
      for (int p = 0; p < 2; ++p){
        long prow = (long)tile*8 + a*2 + p;
        float hs = hv[2*p] + hv[2*p+1];
        HpO[prow*HH + feat] = __builtin_bit_cast(unsigned short, (_Float16)hs);
        csO[prow*HH + feat] = cv[2*p] + cv[2*p+1];
      }
    }
    __syncthreads();
    buf ^= 1;
  }
}

// ---------------- multi-level tail block (generic, single-plane A) ----------
template<int ROWS0, int NLEV, int INPLANES, int FINAL>
__global__ __launch_bounds__(NT, 2) void treeblk2(
    const unsigned short* __restrict__ Hp,
    const float* __restrict__ cs,
    const float* __restrict__ hraw, const float* __restrict__ craw,
    const unsigned short* __restrict__ pE,
    const float* __restrict__ bias,
    float* __restrict__ h_out, float* __restrict__ c_out,
    float* __restrict__ root_out)
{
  constexpr int MT = (ROWS0 >= 16) ? (ROWS0/16) : 1;
  constexpr int AR = (ROWS0 < 16) ? 16 : ROWS0;
  __shared__ float Asum[AR][132];
  __shared__ float Csum[AR][132];

  const int t = threadIdx.x;
  const long blk = blockIdx.x;
  const int w = t >> 6, l = t & 63;
  const int a = l >> 4, fcol = l & 15, feat = w*16 + fcol;

  {
    constexpr int EPT = ROWS0*HH/NT;
    constexpr int TPR = HH/EPT;
    int row = t/TPR, c0 = (t%TPR)*EPT;
    if (INPLANES){
      long base = (blk*ROWS0 + row)*(long)HH + c0;
#pragma unroll
      for (int j = 0; j < EPT; ++j){
        Asum[row][c0+j] = f16_to_f(Hp[base+j]);
        Csum[row][c0+j] = cs[base+j];
      }
    } else {
      long g = (blk*2*ROWS0 + 2*row)*(long)HH + c0;
#pragma unroll
      for (int j = 0; j < EPT; ++j){
        Asum[row][c0+j] = hraw[g+j] + hraw[g+HH+j];
        Csum[row][c0+j] = craw[g+j] + craw[g+HH+j];
      }
    }
    if (ROWS0 < 16){
      int prow2 = ROWS0 + row;
      if (prow2 < 16){
#pragma unroll
        for (int j = 0; j < EPT; ++j){
          Asum[prow2][c0+j] = 0.f;
          Csum[prow2][c0+j] = 0.f;
        }
      }
    }
  }

  f16x8 rb[4][4];
#pragma unroll
  for (int q = 0; q < 4; ++q)
#pragma unroll
    for (int kc = 0; kc < 4; ++kc){
      long off = ((long)((((w>>1)*8) + q*2 + (w&1))*4 + kc)*64 + l)*8;
      rb[q][kc] = *(const f16x8*)&pE[off];
    }
  float B4[4];
#pragma unroll
  for (int q = 0; q < 4; ++q) B4[q] = bias[q*HH + feat];

  __syncthreads();

#pragma unroll
  for (int lv = 0; lv < NLEV; ++lv){
    const int rows  = ROWS0 >> lv;
    const int tiles = (rows >= 16) ? (rows/16) : 1;
    float hv[MT][4], cv[MT][4];

#pragma unroll
    for (int mt = 0; mt < MT; ++mt){
      if (mt >= tiles) continue;
      f16x8 aH[4];
#pragma unroll
      for (int kc = 0; kc < 4; ++kc){
        const float* ap = &Asum[mt*16 + fcol][kc*32 + a*8];
        float av[8];
        *(float4*)&av[0] = *(const float4*)&ap[0];
        *(float4*)&av[4] = *(const float4*)&ap[4];
        unsigned int hp[4];
#pragma unroll
        for (int p = 0; p < 4; ++p) hp[p] = pk16(av[2*p], av[2*p+1]);
        uint4 hq = {hp[0],hp[1],hp[2],hp[3]};
        aH[kc] = *(f16x8*)&hq;
      }
      f32x4 acc[4];
#pragma unroll
      for (int q = 0; q < 4; ++q) acc[q] = (f32x4)(0.f);
#pragma unroll
      for (int kc = 0; kc < 4; ++kc){
#pragma unroll
        for (int q = 0; q < 4; ++q)
          acc[q] = __builtin_amdgcn_mfma_f32_16x16x32_f16(aH[kc], rb[q][kc], acc[q], 0, 0, 0);
      }
#pragma unroll
      for (int rr = 0; rr < 4; ++rr){
        int n = mt*16 + a*4 + rr;
        float ccv = Csum[n][feat];
        float fv = acc[0][rr] + B4[0];
        float iv = acc[1][rr] + B4[1];
        float gv = acc[2][rr] + B4[2];
        float ov = acc[3][rr] + B4[3];
        float c = cell_c(fv, iv, gv, ccv);
        float h = sig_tanh(ov, c);
        hv[mt][rr] = h; cv[mt][rr] = c;
      }
    }
    __syncthreads();

    if (lv < NLEV-1){
#pragma unroll
      for (int mt = 0; mt < MT; ++mt){
        if (mt >= tiles) continue;
#pragma unroll
        for (int p = 0; p < 2; ++p){
          int n0 = mt*16 + a*4 + 2*p;
          if (n0 < rows){
            int prow = n0 >> 1;
            Asum[prow][feat] = hv[mt][2*p] + hv[mt][2*p+1];
            Csum[prow][feat] = cv[mt][2*p] + cv[mt][2*p+1];
          }
        }
      }
      __syncthreads();
    } else if (FINAL){
      if (a == 0) root_out[feat] = hv[0][0];
    } else {
      if (a == 0){
        h_out[blk*HH + feat] = hv[0][0];
        c_out[blk*HH + feat] = cv[0][0];
      }
    }
  }
}

extern "C" void kernel_launch(void* const* d_in, const int* in_sizes, int n_in,
                              void* d_out, int out_size, void* d_ws, size_t ws_size,
                              hipStream_t stream){
  const float* leaf = (const float*)d_in[0];   // 131072 x 128 f32
  const float* W    = (const float*)d_in[1];   // 512 x 256 f32
  const float* bias = (const float*)d_in[2];   // 512 f32
  float* out = (float*)d_out;                  // 128 f32

  unsigned short* pE  = (unsigned short*)d_ws;      // 65536 u16 each
  unsigned short* pL  = pE + 65536;
  unsigned short* HpA = pL + 65536;                 // 2^16 x 128 u16
  unsigned short* HpB = HpA + (1l<<16)*HH;          // 2^14 x 128 u16
  float* csA = (float*)(HpB + (1l<<14)*HH);         // 2^16 x 128 f32
  float* csB = csA + (1l<<16)*HH;                   // 2^14 x 128 f32
  float* h32 = csB + (1l<<14)*HH;                   // 32 x 128 f32
  float* c32 = h32 + 32*HH;

  prep_pack<<<32, PT, 0, stream>>>(W, pE, pL);

  // L0: 2^17 leaves -> 2^16 pair-rows
  leafK<<<512, NT, 0, stream>>>(leaf, pL, bias, HpA, csA, 4096);
  // L1+L2: 2^16 rows -> 2^14
  fuse2<<<512, NT, 0, stream>>>(HpA, csA, pE, bias, HpB, csB, 2048);
  // L3+L4: 2^14 -> 2^12
  fuse2<<<256, NT, 0, stream>>>(HpB, csB, pE, bias, HpA, csA, 512);
  // L5+L6: 2^12 -> 2^10
  fuse2<<<128, NT, 0, stream>>>(HpA, csA, pE, bias, HpB, csB, 128);
  // L7..L12: 2^10 pair-rows -> 32 raw nodes
  treeblk2<32,6,1,0><<<32, NT, 0, stream>>>(HpB, csB, nullptr, nullptr,
                                            pE, bias, h32, c32, nullptr);
  // L13..L17: 32 raw children -> root
  treeblk2<16,5,0,1><<<1, NT, 0, stream>>>(nullptr, nullptr, h32, c32,
                                           pE, bias, nullptr, nullptr, out);

  (void)in_sizes; (void)n_in; (void)out_size; (void)ws_size;
}

// Round 19
// 93.426 us; speedup vs baseline: 1.0582x; 1.0040x over previous
//
#include <hip/hip_runtime.h>

#define HH 128
#define NT 512
#define PT 256

typedef float  f32x4  __attribute__((ext_vector_type(4)));
typedef _Float16 f16x8 __attribute__((ext_vector_type(8)));

// pack two f32 -> u32 of 2 fp16 in ONE inst (v_cvt_pkrtz_f16_f32; elem0 low16)
static __device__ __forceinline__ unsigned int pk16(float a, float b){
  auto r = __builtin_amdgcn_cvt_pkrtz(a, b);
  return __builtin_bit_cast(unsigned int, r);
}
static __device__ __forceinline__ float f16_to_f(unsigned short s){
  return (float)__builtin_bit_cast(_Float16, s);
}

#define K1 1.44269504089f
#define K2 2.88539008178f

// sig(s)*tanh(t) with ONE rcp: (1-e2)/((1+e1)(1+e2))
static __device__ __forceinline__ float sig_tanh(float s, float t){
  float e1 = __builtin_amdgcn_exp2f(-K1*s);
  float e2 = __builtin_amdgcn_exp2f(-K2*t);
  return (1.f - e2) * __builtin_amdgcn_rcpf((1.f + e1)*(1.f + e2));
}
// internal cell c-update with ONE rcp
static __device__ __forceinline__ float cell_c(float fv, float iv, float gv, float cc){
  float ef = __builtin_amdgcn_exp2f(-K1*fv);
  float ei = __builtin_amdgcn_exp2f(-K1*iv);
  float eg = __builtin_amdgcn_exp2f(-K2*gv);
  float pig = (1.f + ei)*(1.f + eg);
  return (cc*pig + (1.f - eg)*(1.f + ef)) * __builtin_amdgcn_rcpf((1.f + ef)*pig);
}

// Pack W into MFMA-B-fragment order, single fp16 RNE plane each.
__global__ __launch_bounds__(PT) void prep_pack(
    const float* __restrict__ W,
    unsigned short* __restrict__ pE, unsigned short* __restrict__ pL)
{
  int idx = blockIdx.x*PT + threadIdx.x;     // 0..8191
  int l  = idx & 63;
  int kc = (idx >> 6) & 3;
  int gl = (idx >> 8) & 7;
  int wp = (idx >> 11);                      // 0..3
  int q  = gl >> 1, ft = gl & 1;
  int g  = q*128 + wp*32 + ft*16 + (l & 15);
  int kbase = kc*32 + (l >> 4)*8;

  unsigned short ev[8], lv[8];
#pragma unroll
  for (int j = 0; j < 8; ++j){
    int k = kbase + j;
    float w0 = W[g*256 + k];
    float w1 = W[g*256 + 128 + k];
    float we = w0 + 0.5f*w1;
    ev[j] = __builtin_bit_cast(unsigned short, (_Float16)we);
    lv[j] = __builtin_bit_cast(unsigned short, (_Float16)w1);
  }
  long base = (long)idx*8;
  *(f16x8*)&pE[base] = *(f16x8*)ev;
  *(f16x8*)&pL[base] = *(f16x8*)lv;
}

// ---------------- leaf kernel: L0 only, single-plane fp16 A ------------------
__global__ __launch_bounds__(NT, 2) void leafK(
    const float* __restrict__ x_leaf,
    const unsigned short* __restrict__ pL,
    const float* __restrict__ bias,
    unsigned short* __restrict__ HpO,
    float* __restrict__ csO, int ntiles)
{
  __shared__ unsigned short AsH[2][32*HH];

  const int t = threadIdx.x, w = t>>6, l = t&63;
  const int a = l>>4, fcol = l&15, feat = w*16 + fcol;

  // resident leaf-B (gates i,g,o): 12 frags = 48 VGPRs
  f16x8 rb[3][4];
#pragma unroll
  for (int qq = 0; qq < 3; ++qq)
#pragma unroll
    for (int kc = 0; kc < 4; ++kc){
      long off = ((long)((((w>>1)*8) + (qq+1)*2 + (w&1))*4 + kc)*64 + l)*8;
      rb[qq][kc] = *(const f16x8*)&pL[off];
    }
  const float Bi = bias[HH + feat], Bg = bias[2*HH + feat], Bo = bias[3*HH + feat];

  const int srow = t>>4, sci = t&15;
  float sv[8];
  auto sload = [&](int tile){
    long base = ((long)tile*32 + srow)*HH + sci*8;
    *(float4*)&sv[0] = *(const float4*)&x_leaf[base];
    *(float4*)&sv[4] = *(const float4*)&x_leaf[base+4];
  };
  auto swrite = [&](int buf){
    unsigned int hp[4];
#pragma unroll
    for (int p = 0; p < 4; ++p) hp[p] = pk16(sv[2*p], sv[2*p+1]);
    uint4 hq = {hp[0],hp[1],hp[2],hp[3]};
    int off = srow*256 + ((sci*16) ^ ((srow&7)<<4));
    *(uint4*)((char*)&AsH[buf][0] + off) = hq;
  };

  int tile = blockIdx.x;
  if (tile < ntiles){ sload(tile); swrite(0); }
  __syncthreads();
  int buf = 0;

  for (; tile < ntiles; tile += gridDim.x){
    // keep B loop-carried
#pragma unroll
    for (int qq = 0; qq < 3; ++qq)
#pragma unroll
      for (int kc = 0; kc < 4; ++kc)
        asm volatile("" : "+v"(rb[qq][kc]));

    int nxt = tile + gridDim.x;
    bool have = nxt < ntiles;
    if (have) sload(nxt);

    f32x4 acc[2][3];
#pragma unroll
    for (int mt = 0; mt < 2; ++mt)
#pragma unroll
      for (int qq = 0; qq < 3; ++qq) acc[mt][qq] = (f32x4)(0.f);

#pragma unroll
    for (int kc = 0; kc < 4; ++kc){
      f16x8 aH[2];
#pragma unroll
      for (int mt = 0; mt < 2; ++mt){
        int row = mt*16 + fcol;
        int off = row*256 + ((kc*64 + a*16) ^ ((row&7)<<4));
        aH[mt] = *(const f16x8*)((const char*)&AsH[buf][0] + off);
      }
#pragma unroll
      for (int qq = 0; qq < 3; ++qq)
#pragma unroll
        for (int mt = 0; mt < 2; ++mt)
          acc[mt][qq] = __builtin_amdgcn_mfma_f32_16x16x32_f16(aH[mt], rb[qq][kc], acc[mt][qq], 0, 0, 0);
    }

    // epilogue (cc = 0): c = sig(i)tanh(g); h = sig(o)tanh(c)
#pragma unroll
    for (int mt = 0; mt < 2; ++mt){
      float hv[4], cv[4];
#pragma unroll
      for (int rr = 0; rr < 4; ++rr){
        float iv = acc[mt][0][rr] + Bi;
        float gv = acc[mt][1][rr] + Bg;
        float ov = acc[mt][2][rr] + Bo;
        float c = sig_tanh(iv, gv);
        float h = sig_tanh(ov, c);
        hv[rr] = h; cv[rr] = c;
      }
#pragma unroll
      for (int p = 0; p < 2; ++p){
        long prow = (long)tile*16 + mt*8 + a*2 + p;
        float hs = hv[2*p] + hv[2*p+1];
        HpO[prow*HH + feat] = __builtin_bit_cast(unsigned short, (_Float16)hs);
        csO[prow*HH + feat] = cv[2*p] + cv[2*p+1];
      }
    }

    if (have) swrite(buf^1);
    __syncthreads();
    buf ^= 1;
  }
}

// ---------------- fused 2-level internal kernel, single-plane fp16 A --------
__global__ __launch_bounds__(NT, 2) void fuse2(
    const unsigned short* __restrict__ hPH,
    const float* __restrict__ cP,
    const unsigned short* __restrict__ pE,
    const float* __restrict__ bias,
    unsigned short* __restrict__ HpO,
    float* __restrict__ csO, int ntiles)
{
  __shared__ unsigned short AsH[2][32*HH];
  __shared__ float HsF[16*HH];
  __shared__ float CsF[16*HH];

  const int t = threadIdx.x, w = t>>6, l = t&63;
  const int a = l>>4, fcol = l&15, feat = w*16 + fcol;

  f16x8 rb[4][4];   // 16 frags = 64 VGPR
#pragma unroll
  for (int q = 0; q < 4; ++q)
#pragma unroll
    for (int kc = 0; kc < 4; ++kc){
      long off = ((long)((((w>>1)*8) + q*2 + (w&1))*4 + kc)*64 + l)*8;
      rb[q][kc] = *(const f16x8*)&pE[off];
    }
  float B4[4];
#pragma unroll
  for (int q = 0; q < 4; ++q) B4[q] = bias[q*HH + feat];

  const int srow = t>>4, sci = t&15;
  f16x8 svH;
  auto sload = [&](int tile){
    long base = ((long)tile*32 + srow)*HH + sci*8;
    svH = *(const f16x8*)&hPH[base];
  };
  auto swrite = [&](int buf){
    int off = srow*256 + ((sci*16) ^ ((srow&7)<<4));
    *(f16x8*)((char*)&AsH[buf][0] + off) = svH;
  };

  int tile = blockIdx.x;
  if (tile < ntiles){ sload(tile); swrite(0); }
  __syncthreads();
  int buf = 0;

  for (; tile < ntiles; tile += gridDim.x){
#pragma unroll
    for (int q = 0; q < 4; ++q)
#pragma unroll
      for (int kc = 0; kc < 4; ++kc)
        asm volatile("" : "+v"(rb[q][kc]));

    int nxt = tile + gridDim.x;
    bool have = nxt < ntiles;

    float cc0[2][4];
#pragma unroll
    for (int mt = 0; mt < 2; ++mt)
#pragma unroll
      for (int rr = 0; rr < 4; ++rr)
        cc0[mt][rr] = cP[((long)tile*32 + mt*16 + a*4 + rr)*HH + feat];

    if (have) sload(nxt);

    // ---- MFMA-0: level A over 32 rows ----
    f32x4 acc0[2][4];
#pragma unroll
    for (int mt = 0; mt < 2; ++mt)
#pragma unroll
      for (int q = 0; q < 4; ++q) acc0[mt][q] = (f32x4)(0.f);

#pragma unroll
    for (int kc = 0; kc < 4; ++kc){
      f16x8 aH[2];
#pragma unroll
      for (int mt = 0; mt < 2; ++mt){
        int row = mt*16 + fcol;
        int off = row*256 + ((kc*64 + a*16) ^ ((row&7)<<4));
        aH[mt] = *(const f16x8*)((const char*)&AsH[buf][0] + off);
      }
#pragma unroll
      for (int q = 0; q < 4; ++q)
#pragma unroll
        for (int mt = 0; mt < 2; ++mt)
          acc0[mt][q] = __builtin_amdgcn_mfma_f32_16x16x32_f16(aH[mt], rb[q][kc], acc0[mt][q], 0, 0, 0);
    }

    // ---- epilogue-0 -> LDS pair-sums (swizzled fp32) ----
#pragma unroll
    for (int mt = 0; mt < 2; ++mt){
      float hv[4], cv[4];
#pragma unroll
      for (int rr = 0; rr < 4; ++rr){
        float fv = acc0[mt][0][rr] + B4[0];
        float iv = acc0[mt][1][rr] + B4[1];
        float gv = acc0[mt][2][rr] + B4[2];
        float ov = acc0[mt][3][rr] + B4[3];
        float c = cell_c(fv, iv, gv, cc0[mt][rr]);
        float h = sig_tanh(ov, c);
        hv[rr] = h; cv[rr] = c;
      }
#pragma unroll
      for (int p = 0; p < 2; ++p){
        int row1 = mt*8 + a*2 + p;
        int o1 = row1*512 + ((feat*4) ^ ((row1&7)<<4));
        *(float*)((char*)HsF + o1) = hv[2*p] + hv[2*p+1];
        *(float*)((char*)CsF + o1) = cv[2*p] + cv[2*p+1];
      }
    }
    if (have) swrite(buf^1);
    __syncthreads();

    // ---- MFMA-1: level B over 16 rows ----
    f32x4 acc1[4];
#pragma unroll
    for (int q = 0; q < 4; ++q) acc1[q] = (f32x4)(0.f);

#pragma unroll
    for (int kc = 0; kc < 4; ++kc){
      f16x8 a1H;
      {
        int cb = kc*128 + a*32;
        const char* base = (const char*)HsF + fcol*512;
        float av[8];
        *(float4*)&av[0] = *(const float4*)(base + ( cb       ^ ((fcol&7)<<4)));
        *(float4*)&av[4] = *(const float4*)(base + ((cb + 16) ^ ((fcol&7)<<4)));
        unsigned int hp[4];
#pragma unroll
        for (int p = 0; p < 4; ++p) hp[p] = pk16(av[2*p], av[2*p+1]);
        uint4 hq = {hp[0],hp[1],hp[2],hp[3]};
        a1H = *(f16x8*)&hq;
      }
#pragma unroll
      for (int q = 0; q < 4; ++q)
        acc1[q] = __builtin_amdgcn_mfma_f32_16x16x32_f16(a1H, rb[q][kc], acc1[q], 0, 0, 0);
    }

    // ---- epilogue-1 -> global planes ----
    {
      float hv[4], cv[4];
#pragma unroll
      for (int rr = 0; rr < 4; ++rr){
        int n = a*4 + rr;
        float ccv = *(const float*)((const char*)CsF + n*512 + ((feat*4) ^ ((n&7)<<4)));
        float fv = acc1[0][rr] + B4[0];
        float iv = acc1[1][rr] + B4[1];
        float gv = acc1[2][rr] + B4[2];
        float ov = acc1[3][rr] + B4[3];
        float c = cell_c(fv, iv, gv, ccv);
        float h = sig_tanh(ov, c);
        hv[rr] = h; cv[rr] = c;
      }
#pragma unroll
      for (int p = 0; p < 2; ++p){
        long prow = (long)tile*8 + a*2 + p;
        float hs = hv[2*p] + hv[2*p+1];
        HpO[prow*HH + feat] = __builtin_bit_cast(unsigned short, (_Float16)hs);
        csO[prow*HH + feat] = cv[2*p] + cv[2*p+1];
      }
    }
    __syncthreads();
    buf ^= 1;
  }
}

// ---------------- multi-level tail block (generic, single-plane A) ----------
template<int ROWS0, int NLEV, int INPLANES, int FINAL>
__global__ __launch_bounds__(NT, 2) void treeblk2(
    const unsigned short* __restrict__ Hp,
    const float* __restrict__ cs,
    const float* __restrict__ hraw, const float* __restrict__ craw,
    const unsigned short* __restrict__ pE,
    const float* __restrict__ bias,
    float* __restrict__ h_out, float* __restrict__ c_out,
    float* __restrict__ root_out)
{
  constexpr int MT = (ROWS0 >= 16) ? (ROWS0/16) : 1;
  constexpr int AR = (ROWS0 < 16) ? 16 : ROWS0;
  __shared__ float Asum[AR][132];
  __shared__ float Csum[AR][132];

  const int t = threadIdx.x;
  const long blk = blockIdx.x;
  const int w = t >> 6, l = t & 63;
  const int a = l >> 4, fcol = l & 15, feat = w*16 + fcol;

  {
    constexpr int EPT = ROWS0*HH/NT;
    constexpr int TPR = HH/EPT;
    int row = t/TPR, c0 = (t%TPR)*EPT;
    if (INPLANES){
      long base = (blk*ROWS0 + row)*(long)HH + c0;
#pragma unroll
      for (int j = 0; j < EPT; ++j){
        Asum[row][c0+j] = f16_to_f(Hp[base+j]);
        Csum[row][c0+j] = cs[base+j];
      }
    } else {
      long g = (blk*2*ROWS0 + 2*row)*(long)HH + c0;
#pragma unroll
      for (int j = 0; j < EPT; ++j){
        Asum[row][c0+j] = hraw[g+j] + hraw[g+HH+j];
        Csum[row][c0+j] = craw[g+j] + craw[g+HH+j];
      }
    }
    if (ROWS0 < 16){
      int prow2 = ROWS0 + row;
      if (prow2 < 16){
#pragma unroll
        for (int j = 0; j < EPT; ++j){
          Asum[prow2][c0+j] = 0.f;
          Csum[prow2][c0+j] = 0.f;
        }
      }
    }
  }

  f16x8 rb[4][4];
#pragma unroll
  for (int q = 0; q < 4; ++q)
#pragma unroll
    for (int kc = 0; kc < 4; ++kc){
      long off = ((long)((((w>>1)*8) + q*2 + (w&1))*4 + kc)*64 + l)*8;
      rb[q][kc] = *(const f16x8*)&pE[off];
    }
  float B4[4];
#pragma unroll
  for (int q = 0; q < 4; ++q) B4[q] = bias[q*HH + feat];

  __syncthreads();

#pragma unroll
  for (int lv = 0; lv < NLEV; ++lv){
    const int rows  = ROWS0 >> lv;
    const int tiles = (rows >= 16) ? (rows/16) : 1;
    float hv[MT][4], cv[MT][4];

#pragma unroll
    for (int mt = 0; mt < MT; ++mt){
      if (mt >= tiles) continue;
      f16x8 aH[4];
#pragma unroll
      for (int kc = 0; kc < 4; ++kc){
        const float* ap = &Asum[mt*16 + fcol][kc*32 + a*8];
        float av[8];
        *(float4*)&av[0] = *(const float4*)&ap[0];
        *(float4*)&av[4] = *(const float4*)&ap[4];
        unsigned int hp[4];
#pragma unroll
        for (int p = 0; p < 4; ++p) hp[p] = pk16(av[2*p], av[2*p+1]);
        uint4 hq = {hp[0],hp[1],hp[2],hp[3]};
        aH[kc] = *(f16x8*)&hq;
      }
      f32x4 acc[4];
#pragma unroll
      for (int q = 0; q < 4; ++q) acc[q] = (f32x4)(0.f);
#pragma unroll
      for (int kc = 0; kc < 4; ++kc){
#pragma unroll
        for (int q = 0; q < 4; ++q)
          acc[q] = __builtin_amdgcn_mfma_f32_16x16x32_f16(aH[kc], rb[q][kc], acc[q], 0, 0, 0);
      }
#pragma unroll
      for (int rr = 0; rr < 4; ++rr){
        int n = mt*16 + a*4 + rr;
        float ccv = Csum[n][feat];
        float fv = acc[0][rr] + B4[0];
        float iv = acc[1][rr] + B4[1];
        float gv = acc[2][rr] + B4[2];
        float ov = acc[3][rr] + B4[3];
        float c = cell_c(fv, iv, gv, ccv);
        float h = sig_tanh(ov, c);
        hv[mt][rr] = h; cv[mt][rr] = c;
      }
    }
    __syncthreads();

    if (lv < NLEV-1){
#pragma unroll
      for (int mt = 0; mt < MT; ++mt){
        if (mt >= tiles) continue;
#pragma unroll
        for (int p = 0; p < 2; ++p){
          int n0 = mt*16 + a*4 + 2*p;
          if (n0 < rows){
            int prow = n0 >> 1;
            Asum[prow][feat] = hv[mt][2*p] + hv[mt][2*p+1];
            Csum[prow][feat] = cv[mt][2*p] + cv[mt][2*p+1];
          }
        }
      }
      __syncthreads();
    } else if (FINAL){
      if (a == 0) root_out[feat] = hv[0][0];
    } else {
      if (a == 0){
        h_out[blk*HH + feat] = hv[0][0];
        c_out[blk*HH + feat] = cv[0][0];
      }
    }
  }
}

extern "C" void kernel_launch(void* const* d_in, const int* in_sizes, int n_in,
                              void* d_out, int out_size, void* d_ws, size_t ws_size,
                              hipStream_t stream){
  const float* leaf = (const float*)d_in[0];   // 131072 x 128 f32
  const float* W    = (const float*)d_in[1];   // 512 x 256 f32
  const float* bias = (const float*)d_in[2];   // 512 f32
  float* out = (float*)d_out;                  // 128 f32

  unsigned short* pE  = (unsigned short*)d_ws;      // 65536 u16 each
  unsigned short* pL  = pE + 65536;
  unsigned short* HpA = pL + 65536;                 // 2^16 x 128 u16
  unsigned short* HpB = HpA + (1l<<16)*HH;          // 2^14 x 128 u16
  float* csA = (float*)(HpB + (1l<<14)*HH);         // 2^16 x 128 f32
  float* csB = csA + (1l<<16)*HH;                   // 2^14 x 128 f32
  float* h128 = csB + (1l<<14)*HH;                  // 128 x 128 f32
  float* c128 = h128 + 128*HH;

  prep_pack<<<32, PT, 0, stream>>>(W, pE, pL);

  // L0: 2^17 leaves -> 2^16 pair-rows
  leafK<<<512, NT, 0, stream>>>(leaf, pL, bias, HpA, csA, 4096);
  // L1+L2: 2^16 rows -> 2^14
  fuse2<<<512, NT, 0, stream>>>(HpA, csA, pE, bias, HpB, csB, 2048);
  // L3+L4: 2^14 -> 2^12
  fuse2<<<256, NT, 0, stream>>>(HpB, csB, pE, bias, HpA, csA, 512);
  // L5..L10: 2^12 pair-rows -> 128 raw nodes (6 levels in LDS, 128 blocks)
  treeblk2<32,6,1,0><<<128, NT, 0, stream>>>(HpA, csA, nullptr, nullptr,
                                             pE, bias, h128, c128, nullptr);
  // L11..L17: 128 raw children -> root (7 levels in LDS)
  treeblk2<64,7,0,1><<<1, NT, 0, stream>>>(nullptr, nullptr, h128, c128,
                                           pE, bias, nullptr, nullptr, out);

  (void)in_sizes; (void)n_in; (void)out_size; (void)ws_size;
}

// Round 20
// 87.486 us; speedup vs baseline: 1.1300x; 1.0679x over previous
//
#include <hip/hip_runtime.h>

#define HH 128
#define NT 512
#define PT 256

typedef float  f32x4  __attribute__((ext_vector_type(4)));
typedef _Float16 f16x8 __attribute__((ext_vector_type(8)));

#define K1 1.44269504089f
#define K2 2.88539008178f

// pack two f32 -> u32 of 2 fp16 in ONE inst (v_cvt_pkrtz_f16_f32; elem0 low16)
static __device__ __forceinline__ unsigned int pk16(float a, float b){
  auto r = __builtin_amdgcn_cvt_pkrtz(a, b);
  return __builtin_bit_cast(unsigned int, r);
}
static __device__ __forceinline__ float f16_to_f(unsigned short s){
  return (float)__builtin_bit_cast(_Float16, s);
}

// PRESCALED gates: MFMA outputs are already -K1*f, -K1*i, -K2*g, -K1*o.
// leaf cell (cc=0): ei,eg,eo = exp2(acc)
static __device__ __forceinline__ void leaf_cell(float ai, float ag, float ao,
                                                float& h, float& c){
  float ei = __builtin_amdgcn_exp2f(ai);
  float eg = __builtin_amdgcn_exp2f(ag);
  float eo = __builtin_amdgcn_exp2f(ao);
  c = (1.f - eg) * __builtin_amdgcn_rcpf((1.f + ei)*(1.f + eg));
  float e2 = __builtin_amdgcn_exp2f(-K2*c);
  h = (1.f - e2) * __builtin_amdgcn_rcpf((1.f + eo)*(1.f + e2));
}
// internal cell: af..ao prescaled; cc plain
static __device__ __forceinline__ void int_cell(float af, float ai, float ag,
                                                float ao, float cc,
                                                float& h, float& c){
  float ef = __builtin_amdgcn_exp2f(af);
  float ei = __builtin_amdgcn_exp2f(ai);
  float eg = __builtin_amdgcn_exp2f(ag);
  float eo = __builtin_amdgcn_exp2f(ao);
  float pig = (1.f + ei)*(1.f + eg);
  c = (cc*pig + (1.f - eg)*(1.f + ef)) * __builtin_amdgcn_rcpf((1.f + ef)*pig);
  float e2 = __builtin_amdgcn_exp2f(-K2*c);
  h = (1.f - e2) * __builtin_amdgcn_rcpf((1.f + eo)*(1.f + e2));
}

// Pack W into MFMA-B-fragment order, fp16, PRESCALED by -K1 (q!=2) / -K2 (q==2).
__global__ __launch_bounds__(PT) void prep_pack(
    const float* __restrict__ W,
    unsigned short* __restrict__ pE, unsigned short* __restrict__ pL)
{
  int idx = blockIdx.x*PT + threadIdx.x;     // 0..8191
  int l  = idx & 63;
  int kc = (idx >> 6) & 3;
  int gl = (idx >> 8) & 7;
  int wp = (idx >> 11);                      // 0..3
  int q  = gl >> 1, ft = gl & 1;
  int g  = q*128 + wp*32 + ft*16 + (l & 15);
  int kbase = kc*32 + (l >> 4)*8;
  float S = (q == 2) ? -K2 : -K1;

  unsigned short ev[8], lv[8];
#pragma unroll
  for (int j = 0; j < 8; ++j){
    int k = kbase + j;
    float w0 = W[g*256 + k];
    float w1 = W[g*256 + 128 + k];
    float we = w0 + 0.5f*w1;
    ev[j] = __builtin_bit_cast(unsigned short, (_Float16)(S*we));
    lv[j] = __builtin_bit_cast(unsigned short, (_Float16)(S*w1));
  }
  long base = (long)idx*8;
  *(f16x8*)&pE[base] = *(f16x8*)ev;
  *(f16x8*)&pL[base] = *(f16x8*)lv;
}

// ---------------- leaf kernel: L0 only, single-plane fp16 A ------------------
__global__ __launch_bounds__(NT, 2) void leafK(
    const float* __restrict__ x_leaf,
    const unsigned short* __restrict__ pL,
    const float* __restrict__ bias,
    unsigned short* __restrict__ HpO,
    float* __restrict__ csO, int ntiles)
{
  __shared__ unsigned short AsH[2][32*HH];

  const int t = threadIdx.x, w = t>>6, l = t&63;
  const int a = l>>4, fcol = l&15, feat = w*16 + fcol;

  // resident leaf-B (gates i,g,o): 12 frags = 48 VGPRs
  f16x8 rb[3][4];
#pragma unroll
  for (int qq = 0; qq < 3; ++qq)
#pragma unroll
    for (int kc = 0; kc < 4; ++kc){
      long off = ((long)((((w>>1)*8) + (qq+1)*2 + (w&1))*4 + kc)*64 + l)*8;
      rb[qq][kc] = *(const f16x8*)&pL[off];
    }
  // prescaled biases (match W prescale)
  const float Bi = -K1*bias[HH + feat];
  const float Bg = -K2*bias[2*HH + feat];
  const float Bo = -K1*bias[3*HH + feat];

  const int srow = t>>4, sci = t&15;
  float sv[8];
  auto sload = [&](int tile){
    long base = ((long)tile*32 + srow)*HH + sci*8;
    *(float4*)&sv[0] = *(const float4*)&x_leaf[base];
    *(float4*)&sv[4] = *(const float4*)&x_leaf[base+4];
  };
  auto swrite = [&](int buf){
    unsigned int hp[4];
#pragma unroll
    for (int p = 0; p < 4; ++p) hp[p] = pk16(sv[2*p], sv[2*p+1]);
    uint4 hq = {hp[0],hp[1],hp[2],hp[3]};
    int off = srow*256 + ((sci*16) ^ ((srow&7)<<4));
    *(uint4*)((char*)&AsH[buf][0] + off) = hq;
  };

  int tile = blockIdx.x;
  if (tile < ntiles){ sload(tile); swrite(0); }
  __syncthreads();
  int buf = 0;

  for (; tile < ntiles; tile += gridDim.x){
#pragma unroll
    for (int qq = 0; qq < 3; ++qq)
#pragma unroll
      for (int kc = 0; kc < 4; ++kc)
        asm volatile("" : "+v"(rb[qq][kc]));

    int nxt = tile + gridDim.x;
    bool have = nxt < ntiles;
    if (have) sload(nxt);

    // bias folded into accumulator init (col-only -> same across 4 row-regs)
    f32x4 acc[2][3];
#pragma unroll
    for (int mt = 0; mt < 2; ++mt){
      acc[mt][0] = (f32x4)(Bi);
      acc[mt][1] = (f32x4)(Bg);
      acc[mt][2] = (f32x4)(Bo);
    }

#pragma unroll
    for (int kc = 0; kc < 4; ++kc){
      f16x8 aH[2];
#pragma unroll
      for (int mt = 0; mt < 2; ++mt){
        int row = mt*16 + fcol;
        int off = row*256 + ((kc*64 + a*16) ^ ((row&7)<<4));
        aH[mt] = *(const f16x8*)((const char*)&AsH[buf][0] + off);
      }
#pragma unroll
      for (int qq = 0; qq < 3; ++qq)
#pragma unroll
        for (int mt = 0; mt < 2; ++mt)
          acc[mt][qq] = __builtin_amdgcn_mfma_f32_16x16x32_f16(aH[mt], rb[qq][kc], acc[mt][qq], 0, 0, 0);
    }

    // epilogue (cc = 0)
#pragma unroll
    for (int mt = 0; mt < 2; ++mt){
      float hv[4], cv[4];
#pragma unroll
      for (int rr = 0; rr < 4; ++rr)
        leaf_cell(acc[mt][0][rr], acc[mt][1][rr], acc[mt][2][rr], hv[rr], cv[rr]);
#pragma unroll
      for (int p = 0; p < 2; ++p){
        long prow = (long)tile*16 + mt*8 + a*2 + p;
        float hs = hv[2*p] + hv[2*p+1];
        HpO[prow*HH + feat] = __builtin_bit_cast(unsigned short, (_Float16)hs);
        csO[prow*HH + feat] = cv[2*p] + cv[2*p+1];
      }
    }

    if (have) swrite(buf^1);
    __syncthreads();
    buf ^= 1;
  }
}

// ---------------- fused 2-level internal kernel, f16 HsF --------------------
__global__ __launch_bounds__(NT, 2) void fuse2(
    const unsigned short* __restrict__ hPH,
    const float* __restrict__ cP,
    const unsigned short* __restrict__ pE,
    const float* __restrict__ bias,
    unsigned short* __restrict__ HpO,
    float* __restrict__ csO, int ntiles)
{
  __shared__ unsigned short AsH[2][32*HH];
  __shared__ unsigned short HsF[16*HH];   // f16 inter-level h (4KB)
  __shared__ float          CsF[16*HH];   // f32 inter-level c (8KB)

  const int t = threadIdx.x, w = t>>6, l = t&63;
  const int a = l>>4, fcol = l&15, feat = w*16 + fcol;

  f16x8 rb[4][4];
#pragma unroll
  for (int q = 0; q < 4; ++q)
#pragma unroll
    for (int kc = 0; kc < 4; ++kc){
      long off = ((long)((((w>>1)*8) + q*2 + (w&1))*4 + kc)*64 + l)*8;
      rb[q][kc] = *(const f16x8*)&pE[off];
    }
  float B4[4];
#pragma unroll
  for (int q = 0; q < 4; ++q)
    B4[q] = ((q == 2) ? -K2 : -K1) * bias[q*HH + feat];

  const int srow = t>>4, sci = t&15;
  f16x8 svH;
  auto sload = [&](int tile){
    long base = ((long)tile*32 + srow)*HH + sci*8;
    svH = *(const f16x8*)&hPH[base];
  };
  auto swrite = [&](int buf){
    int off = srow*256 + ((sci*16) ^ ((srow&7)<<4));
    *(f16x8*)((char*)&AsH[buf][0] + off) = svH;
  };

  int tile = blockIdx.x;
  if (tile < ntiles){ sload(tile); swrite(0); }
  __syncthreads();
  int buf = 0;

  for (; tile < ntiles; tile += gridDim.x){
#pragma unroll
    for (int q = 0; q < 4; ++q)
#pragma unroll
      for (int kc = 0; kc < 4; ++kc)
        asm volatile("" : "+v"(rb[q][kc]));

    int nxt = tile + gridDim.x;
    bool have = nxt < ntiles;

    float cc0[2][4];
#pragma unroll
    for (int mt = 0; mt < 2; ++mt)
#pragma unroll
      for (int rr = 0; rr < 4; ++rr)
        cc0[mt][rr] = cP[((long)tile*32 + mt*16 + a*4 + rr)*HH + feat];

    if (have) sload(nxt);

    // ---- MFMA-0: level A over 32 rows (bias in acc init) ----
    f32x4 acc0[2][4];
#pragma unroll
    for (int mt = 0; mt < 2; ++mt)
#pragma unroll
      for (int q = 0; q < 4; ++q) acc0[mt][q] = (f32x4)(B4[q]);

#pragma unroll
    for (int kc = 0; kc < 4; ++kc){
      f16x8 aH[2];
#pragma unroll
      for (int mt = 0; mt < 2; ++mt){
        int row = mt*16 + fcol;
        int off = row*256 + ((kc*64 + a*16) ^ ((row&7)<<4));
        aH[mt] = *(const f16x8*)((const char*)&AsH[buf][0] + off);
      }
#pragma unroll
      for (int q = 0; q < 4; ++q)
#pragma unroll
        for (int mt = 0; mt < 2; ++mt)
          acc0[mt][q] = __builtin_amdgcn_mfma_f32_16x16x32_f16(aH[mt], rb[q][kc], acc0[mt][q], 0, 0, 0);
    }

    // ---- epilogue-0 -> LDS pair-sums (f16 h, f32 c) ----
#pragma unroll
    for (int mt = 0; mt < 2; ++mt){
      float hv[4], cv[4];
#pragma unroll
      for (int rr = 0; rr < 4; ++rr)
        int_cell(acc0[mt][0][rr], acc0[mt][1][rr], acc0[mt][2][rr], acc0[mt][3][rr],
                 cc0[mt][rr], hv[rr], cv[rr]);
#pragma unroll
      for (int p = 0; p < 2; ++p){
        int row1 = mt*8 + a*2 + p;
        float hs = hv[2*p] + hv[2*p+1];
        *(unsigned short*)((char*)HsF + row1*256 + ((feat*2) ^ ((row1&7)<<4))) =
            __builtin_bit_cast(unsigned short, (_Float16)hs);
        *(float*)((char*)CsF + row1*512 + ((feat*4) ^ ((row1&7)<<4))) =
            cv[2*p] + cv[2*p+1];
      }
    }
    if (have) swrite(buf^1);
    __syncthreads();

    // ---- MFMA-1: level B over 16 rows, A direct from f16 LDS ----
    f32x4 acc1[4];
#pragma unroll
    for (int q = 0; q < 4; ++q) acc1[q] = (f32x4)(B4[q]);
#pragma unroll
    for (int kc = 0; kc < 4; ++kc){
      int off = fcol*256 + ((kc*64 + a*16) ^ ((fcol&7)<<4));
      f16x8 a1H = *(const f16x8*)((const char*)HsF + off);
#pragma unroll
      for (int q = 0; q < 4; ++q)
        acc1[q] = __builtin_amdgcn_mfma_f32_16x16x32_f16(a1H, rb[q][kc], acc1[q], 0, 0, 0);
    }

    // ---- epilogue-1 -> global planes ----
    {
      float hv[4], cv[4];
#pragma unroll
      for (int rr = 0; rr < 4; ++rr){
        int n = a*4 + rr;
        float ccv = *(const float*)((const char*)CsF + n*512 + ((feat*4) ^ ((n&7)<<4)));
        int_cell(acc1[0][rr], acc1[1][rr], acc1[2][rr], acc1[3][rr], ccv, hv[rr], cv[rr]);
      }
#pragma unroll
      for (int p = 0; p < 2; ++p){
        long prow = (long)tile*8 + a*2 + p;
        float hs = hv[2*p] + hv[2*p+1];
        HpO[prow*HH + feat] = __builtin_bit_cast(unsigned short, (_Float16)hs);
        csO[prow*HH + feat] = cv[2*p] + cv[2*p+1];
      }
    }
    __syncthreads();
    buf ^= 1;
  }
}

// ---------------- multi-level tail block (generic, single-plane A) ----------
template<int ROWS0, int NLEV, int INPLANES, int FINAL>
__global__ __launch_bounds__(NT, 2) void treeblk2(
    const unsigned short* __restrict__ Hp,
    const float* __restrict__ cs,
    const float* __restrict__ hraw, const float* __restrict__ craw,
    const unsigned short* __restrict__ pE,
    const float* __restrict__ bias,
    float* __restrict__ h_out, float* __restrict__ c_out,
    float* __restrict__ root_out)
{
  constexpr int MT = (ROWS0 >= 16) ? (ROWS0/16) : 1;
  constexpr int AR = (ROWS0 < 16) ? 16 : ROWS0;
  __shared__ float Asum[AR][132];
  __shared__ float Csum[AR][132];

  const int t = threadIdx.x;
  const long blk = blockIdx.x;
  const int w = t >> 6, l = t & 63;
  const int a = l >> 4, fcol = l & 15, feat = w*16 + fcol;

  {
    constexpr int EPT = ROWS0*HH/NT;
    constexpr int TPR = HH/EPT;
    int row = t/TPR, c0 = (t%TPR)*EPT;
    if (INPLANES){
      long base = (blk*ROWS0 + row)*(long)HH + c0;
#pragma unroll
      for (int j = 0; j < EPT; ++j){
        Asum[row][c0+j] = f16_to_f(Hp[base+j]);
        Csum[row][c0+j] = cs[base+j];
      }
    } else {
      long g = (blk*2*ROWS0 + 2*row)*(long)HH + c0;
#pragma unroll
      for (int j = 0; j < EPT; ++j){
        Asum[row][c0+j] = hraw[g+j] + hraw[g+HH+j];
        Csum[row][c0+j] = craw[g+j] + craw[g+HH+j];
      }
    }
    if (ROWS0 < 16){
      int prow2 = ROWS0 + row;
      if (prow2 < 16){
#pragma unroll
        for (int j = 0; j < EPT; ++j){
          Asum[prow2][c0+j] = 0.f;
          Csum[prow2][c0+j] = 0.f;
        }
      }
    }
  }

  f16x8 rb[4][4];
#pragma unroll
  for (int q = 0; q < 4; ++q)
#pragma unroll
    for (int kc = 0; kc < 4; ++kc){
      long off = ((long)((((w>>1)*8) + q*2 + (w&1))*4 + kc)*64 + l)*8;
      rb[q][kc] = *(const f16x8*)&pE[off];
    }
  float B4[4];
#pragma unroll
  for (int q = 0; q < 4; ++q)
    B4[q] = ((q == 2) ? -K2 : -K1) * bias[q*HH + feat];

  __syncthreads();

#pragma unroll
  for (int lv = 0; lv < NLEV; ++lv){
    const int rows  = ROWS0 >> lv;
    const int tiles = (rows >= 16) ? (rows/16) : 1;
    float hv[MT][4], cv[MT][4];

#pragma unroll
    for (int mt = 0; mt < MT; ++mt){
      if (mt >= tiles) continue;
      f16x8 aH[4];
#pragma unroll
      for (int kc = 0; kc < 4; ++kc){
        const float* ap = &Asum[mt*16 + fcol][kc*32 + a*8];
        float av[8];
        *(float4*)&av[0] = *(const float4*)&ap[0];
        *(float4*)&av[4] = *(const float4*)&ap[4];
        unsigned int hp[4];
#pragma unroll
        for (int p = 0; p < 4; ++p) hp[p] = pk16(av[2*p], av[2*p+1]);
        uint4 hq = {hp[0],hp[1],hp[2],hp[3]};
        aH[kc] = *(f16x8*)&hq;
      }
      f32x4 acc[4];
#pragma unroll
      for (int q = 0; q < 4; ++q) acc[q] = (f32x4)(B4[q]);
#pragma unroll
      for (int kc = 0; kc < 4; ++kc){
#pragma unroll
        for (int q = 0; q < 4; ++q)
          acc[q] = __builtin_amdgcn_mfma_f32_16x16x32_f16(aH[kc], rb[q][kc], acc[q], 0, 0, 0);
      }
#pragma unroll
      for (int rr = 0; rr < 4; ++rr){
        int n = mt*16 + a*4 + rr;
        int_cell(acc[0][rr], acc[1][rr], acc[2][rr], acc[3][rr],
                 Csum[n][feat], hv[mt][rr], cv[mt][rr]);
      }
    }
    __syncthreads();

    if (lv < NLEV-1){
#pragma unroll
      for (int mt = 0; mt < MT; ++mt){
        if (mt >= tiles) continue;
#pragma unroll
        for (int p = 0; p < 2; ++p){
          int n0 = mt*16 + a*4 + 2*p;
          if (n0 < rows){
            int prow = n0 >> 1;
            Asum[prow][feat] = hv[mt][2*p] + hv[mt][2*p+1];
            Csum[prow][feat] = cv[mt][2*p] + cv[mt][2*p+1];
          }
        }
      }
      __syncthreads();
    } else if (FINAL){
      if (a == 0) root_out[feat] = hv[0][0];
    } else {
      if (a == 0){
        h_out[blk*HH + feat] = hv[0][0];
        c_out[blk*HH + feat] = cv[0][0];
      }
    }
  }
}

extern "C" void kernel_launch(void* const* d_in, const int* in_sizes, int n_in,
                              void* d_out, int out_size, void* d_ws, size_t ws_size,
                              hipStream_t stream){
  const float* leaf = (const float*)d_in[0];   // 131072 x 128 f32
  const float* W    = (const float*)d_in[1];   // 512 x 256 f32
  const float* bias = (const float*)d_in[2];   // 512 f32
  float* out = (float*)d_out;                  // 128 f32

  unsigned short* pE  = (unsigned short*)d_ws;      // 65536 u16 each
  unsigned short* pL  = pE + 65536;
  unsigned short* HpA = pL + 65536;                 // 2^16 x 128 u16
  unsigned short* HpB = HpA + (1l<<16)*HH;          // 2^14 x 128 u16
  float* csA = (float*)(HpB + (1l<<14)*HH);         // 2^16 x 128 f32
  float* csB = csA + (1l<<16)*HH;                   // 2^14 x 128 f32
  float* h128 = csB + (1l<<14)*HH;                  // 128 x 128 f32
  float* c128 = h128 + 128*HH;

  prep_pack<<<32, PT, 0, stream>>>(W, pE, pL);

  // L0: 2^17 leaves -> 2^16 pair-rows
  leafK<<<512, NT, 0, stream>>>(leaf, pL, bias, HpA, csA, 4096);
  // L1+L2: 2^16 rows -> 2^14
  fuse2<<<512, NT, 0, stream>>>(HpA, csA, pE, bias, HpB, csB, 2048);
  // L3+L4: 2^14 -> 2^12
  fuse2<<<256, NT, 0, stream>>>(HpB, csB, pE, bias, HpA, csA, 512);
  // L5..L10: 2^12 pair-rows -> 128 raw nodes (6 levels in LDS, 128 blocks)
  treeblk2<32,6,1,0><<<128, NT, 0, stream>>>(HpA, csA, nullptr, nullptr,
                                             pE, bias, h128, c128, nullptr);
  // L11..L17: 128 raw children -> root (7 levels in LDS)
  treeblk2<64,7,0,1><<<1, NT, 0, stream>>>(nullptr, nullptr, h128, c128,
                                           pE, bias, nullptr, nullptr, out);

  (void)in_sizes; (void)n_in; (void)out_size; (void)ws_size;
}